// Round 6
// baseline (75.259 us; speedup 1.0000x reference)
//
#include <hip/hip_runtime.h>

#define NN 2048
#define KK 512

typedef __attribute__((ext_vector_type(8))) short bf16x8;
typedef __attribute__((ext_vector_type(4))) float f32x4;

__device__ inline ushort f2bf(float x) {  // RNE f32->bf16
  union { float f; unsigned u; } v; v.f = x;
  unsigned r = v.u + 0x7fffu + ((v.u >> 16) & 1u);
  return (ushort)(r >> 16);
}

// -------- K0: W -> WT_hi/WT_lo (bf16 split, [n][k] layout). grid 32 --------
__global__ __launch_bounds__(256) void k_wprep(
    const float* __restrict__ W, ushort* __restrict__ wthi,
    ushort* __restrict__ wtlo) {
  __shared__ float ts[64][65];
  const int t = threadIdx.x;
  const int kb = (blockIdx.x >> 2) * 64;
  const int nb = (blockIdx.x & 3) * 64;
  const int r = t >> 6, c = t & 63;
#pragma unroll
  for (int p = 0; p < 16; ++p)
    ts[p * 4 + r][c] = W[(size_t)(kb + p * 4 + r) * 256 + nb + c];
  __syncthreads();
#pragma unroll
  for (int p = 0; p < 16; ++p) {
    int n = p * 4 + r;
    int k = c;
    float v = ts[k][n];
    union { float f; unsigned u; } q; q.f = v;
    ushort hi = (ushort)(q.u >> 16);
    union { float f; unsigned u; } hf; hf.u = q.u & 0xffff0000u;
    ushort lo = f2bf(v - hf.f);
    size_t off = (size_t)(nb + n) * KK + kb + k;
    wthi[off] = hi;
    wtlo[off] = lo;
  }
}

// -------- K1: g = h@W via split-bf16 MFMA; writes gTb (tiled bf16), el, er --
// grid 128 (16 rows each), block 256 (wave = head)
__global__ __launch_bounds__(256) void k_gemm(
    const float* __restrict__ hin, const ushort* __restrict__ wthi,
    const ushort* __restrict__ wtlo, const float* __restrict__ aw,
    ushort* __restrict__ gTb, float* __restrict__ el, float* __restrict__ er) {
  __shared__ float hs[16][516];
  const int tid = threadIdx.x;
  const int i0 = blockIdx.x * 16;
#pragma unroll
  for (int p = 0; p < 8; ++p) {
    int g4 = tid + p * 256;
    int row = g4 >> 7, col = (g4 & 127) << 2;
    *(float4*)&hs[row][col] = *(const float4*)(hin + (size_t)(i0 + row) * KK + col);
  }
  __syncthreads();

  const int h = tid >> 6;
  const int lane = tid & 63;
  const int il = lane & 15;
  const int kg = lane >> 4;

  f32x4 acc[4];
#pragma unroll
  for (int nt = 0; nt < 4; ++nt) acc[nt] = (f32x4){0.f, 0.f, 0.f, 0.f};

  const ushort* bh_base = wthi + (size_t)(h * 64 + il) * KK;
  const ushort* bl_base = wtlo + (size_t)(h * 64 + il) * KK;

#pragma unroll 4
  for (int ks = 0; ks < 16; ++ks) {
    const int ko = ks * 32 + kg * 8;
    float4 a01 = *(const float4*)&hs[il][ko];
    float4 a23 = *(const float4*)&hs[il][ko + 4];
    float av[8] = {a01.x, a01.y, a01.z, a01.w, a23.x, a23.y, a23.z, a23.w};
    union { unsigned u[4]; bf16x8 v; } Ah, Al;
#pragma unroll
    for (int p = 0; p < 4; ++p) {
      union { float f; unsigned u; } u0, u1;
      u0.f = av[2 * p]; u1.f = av[2 * p + 1];
      Ah.u[p] = (u0.u >> 16) | (u1.u & 0xffff0000u);
      union { float f; unsigned u; } h0, h1;
      h0.u = u0.u & 0xffff0000u;
      h1.u = u1.u & 0xffff0000u;
      union { float f; unsigned u; } r0, r1;
      r0.f = av[2 * p] - h0.f;
      r1.f = av[2 * p + 1] - h1.f;
      Al.u[p] = (r0.u >> 16) | (r1.u & 0xffff0000u);
    }
#pragma unroll
    for (int nt = 0; nt < 4; ++nt) {
      bf16x8 Bh = *(const bf16x8*)(bh_base + nt * 16 * KK + ko);
      bf16x8 Bl = *(const bf16x8*)(bl_base + nt * 16 * KK + ko);
      acc[nt] = __builtin_amdgcn_mfma_f32_16x16x32_bf16(Ah.v, Bh, acc[nt], 0, 0, 0);
      acc[nt] = __builtin_amdgcn_mfma_f32_16x16x32_bf16(Al.v, Bh, acc[nt], 0, 0, 0);
      acc[nt] = __builtin_amdgcn_mfma_f32_16x16x32_bf16(Ah.v, Bl, acc[nt], 0, 0, 0);
    }
  }

  // gTb write: layout [j/8][f][8] bf16, C/D: col(il)=n=f, row(kg*4+q)=i=j
  const int jb = (i0 >> 3) + (kg >> 1);
  const int halfoff = (kg & 1) * 4;
#pragma unroll
  for (int nt = 0; nt < 4; ++nt) {
    const int f = h * 64 + nt * 16 + il;
    unsigned w0 = (unsigned)f2bf(acc[nt][0]) | ((unsigned)f2bf(acc[nt][1]) << 16);
    unsigned w1 = (unsigned)f2bf(acc[nt][2]) | ((unsigned)f2bf(acc[nt][3]) << 16);
    uint2 pk = make_uint2(w0, w1);
    *(uint2*)(gTb + (size_t)jb * 2048 + f * 8 + halfoff) = pk;
  }

  // el/er epilogue
  float ela[4] = {0.f, 0.f, 0.f, 0.f}, era[4] = {0.f, 0.f, 0.f, 0.f};
#pragma unroll
  for (int nt = 0; nt < 4; ++nt) {
    float as = aw[nt * 16 + il];
    float ad = aw[64 + nt * 16 + il];
#pragma unroll
    for (int q = 0; q < 4; ++q) {
      ela[q] += acc[nt][q] * as;
      era[q] += acc[nt][q] * ad;
    }
  }
#pragma unroll
  for (int m = 1; m < 16; m <<= 1) {
#pragma unroll
    for (int q = 0; q < 4; ++q) {
      ela[q] += __shfl_xor(ela[q], m);
      era[q] += __shfl_xor(era[q], m);
    }
  }
  if (il == 0) {
#pragma unroll
    for (int q = 0; q < 4; ++q) {
      el[(i0 + kg * 4 + q) * 4 + h] = ela[q];
      er[(i0 + kg * 4 + q) * 4 + h] = era[q];
    }
  }
}

// -------- K2: exp tables from el/er. grid 8 --------
__global__ __launch_bounds__(256) void k_tables(
    const float* __restrict__ el, const float* __restrict__ er,
    float* __restrict__ Eel, float* __restrict__ Fel,
    float* __restrict__ Eer_jh, float* __restrict__ Fer_jh,
    float* __restrict__ Eer_hj, float* __restrict__ Fer_hj) {
  const int idx = blockIdx.x * 256 + threadIdx.x;
  float4 e4 = *(const float4*)(el + idx * 4);
  float4 r4 = *(const float4*)(er + idx * 4);
  float el_[4] = {e4.x, e4.y, e4.z, e4.w};
  float er_[4] = {r4.x, r4.y, r4.z, r4.w};
  float eel[4], fel[4], eer[4], fer[4];
#pragma unroll
  for (int h = 0; h < 4; ++h) {
    eel[h] = __expf(el_[h]);
    fel[h] = __expf(0.2f * el_[h]);
    eer[h] = __expf(er_[h]);
    fer[h] = __expf(0.2f * er_[h]);
  }
  *(float4*)(Eel + idx * 4) = make_float4(eel[0], eel[1], eel[2], eel[3]);
  *(float4*)(Fel + idx * 4) = make_float4(fel[0], fel[1], fel[2], fel[3]);
  *(float4*)(Eer_jh + idx * 4) = make_float4(eer[0], eer[1], eer[2], eer[3]);
  *(float4*)(Fer_jh + idx * 4) = make_float4(fer[0], fer[1], fer[2], fer[3]);
#pragma unroll
  for (int h = 0; h < 4; ++h) {
    Eer_hj[h * NN + idx] = eer[h];
    Fer_hj[h * NN + idx] = fer[h];
  }
}

// -------- K3: Z1[h], Z2 + adjacency bitmask. grid 2048 (block = row) -------
__global__ __launch_bounds__(256) void k_rowz(
    const float* __restrict__ adj, const float* __restrict__ s,
    const float* __restrict__ Eel, const float* __restrict__ Fel,
    const float* __restrict__ Eer_jh, const float* __restrict__ Fer_jh,
    float* __restrict__ rZ1, float* __restrict__ rZ2,
    unsigned long long* __restrict__ maskb) {
  const int row = blockIdx.x;
  const int tid = threadIdx.x;
  const int wq = tid >> 6;
  const int lane = tid & 63;

  float4 e4 = *(const float4*)(Eel + row * 4);
  float4 f4 = *(const float4*)(Fel + row * 4);
  const float eel[4] = {e4.x, e4.y, e4.z, e4.w};
  const float fel[4] = {f4.x, f4.y, f4.z, f4.w};

  float z1[4] = {0.f, 0.f, 0.f, 0.f};
  float z2 = 0.f;

  const float* ap = adj + (size_t)row * NN + wq * 512;
  const float* sp = s + (size_t)row * NN + wq * 512;

#pragma unroll
  for (int it = 0; it < 8; ++it) {
    const int j = it * 64 + lane;
    float a = ap[j];
    float sv = sp[j];
    bool nb = (a != 0.f);
    unsigned long long m = __ballot(nb);
    if (lane == 0) maskb[row * 32 + wq * 8 + it] = m;
    const int jg = wq * 512 + j;
    float4 eer4 = *(const float4*)(Eer_jh + jg * 4);
    float4 fer4 = *(const float4*)(Fer_jh + jg * 4);
    z2 += nb ? __expf(sv) : 0.f;
    float ev[4] = {eer4.x, eer4.y, eer4.z, eer4.w};
    float fv[4] = {fer4.x, fer4.y, fer4.z, fer4.w};
#pragma unroll
    for (int h = 0; h < 4; ++h) {
      float p = eel[h] * ev[h];
      float q = fel[h] * fv[h];
      float E = fmaxf(p, q);  // == (p>1 ? p : q), exp monotone
      z1[h] += nb ? E : 0.f;
    }
  }

#pragma unroll
  for (int m = 1; m < 64; m <<= 1) {
    z2 += __shfl_xor(z2, m);
#pragma unroll
    for (int h = 0; h < 4; ++h) z1[h] += __shfl_xor(z1[h], m);
  }

  __shared__ float wr[4][5];
  if (lane == 0) {
    wr[wq][0] = z1[0]; wr[wq][1] = z1[1]; wr[wq][2] = z1[2]; wr[wq][3] = z1[3];
    wr[wq][4] = z2;
  }
  __syncthreads();
  if (tid < 5) {
    float sum = wr[0][tid] + wr[1][tid] + wr[2][tid] + wr[3][tid];
    if (tid < 4) rZ1[row * 4 + tid] = 1.f / sum;
    else rZ2[row] = 1.f / sum;
  }
}

// -------- K4: coefficient + MFMA contraction. grid 2048 -------------------
// wave = head h; lane: il = lane&15 (i-row), kg = lane>>4 (k-group)
__global__ __launch_bounds__(256, 8) void k_attn(
    const float* __restrict__ s, const unsigned long long* __restrict__ maskb,
    const ushort* __restrict__ gTb,
    const float* __restrict__ Eel, const float* __restrict__ Fel,
    const float* __restrict__ Eer_hj, const float* __restrict__ Fer_hj,
    const float* __restrict__ rZ1, const float* __restrict__ rZ2,
    _Float16* __restrict__ U, float* __restrict__ Z3p) {
  const int tid = threadIdx.x;
  const int h = tid >> 6;
  const int lane = tid & 63;
  const int il = lane & 15;
  const int kg = lane >> 4;
  const int ib = blockIdx.x >> 4;
  const int jc = blockIdx.x & 15;
  const int i0 = ib * 16;
  const int jb0 = jc * 128;
  const int row = i0 + il;

  const float eel = Eel[row * 4 + h];
  const float fel = Fel[row * 4 + h];
  const float rz1 = rZ1[row * 4 + h];
  const float rz2 = rZ2[row];

  const unsigned long long* mp = maskb + row * 32 + jc * 2;
  const unsigned long long m0 = mp[0];
  const unsigned long long m1 = mp[1];

  f32x4 acc[4];
#pragma unroll
  for (int nt = 0; nt < 4; ++nt) acc[nt] = (f32x4){0.f, 0.f, 0.f, 0.f};
  float z3 = 0.f;

  const float* sp = s + (size_t)row * NN + jb0 + kg * 8;
  const float* eerp = Eer_hj + h * NN + jb0 + kg * 8;
  const float* ferp = Fer_hj + h * NN + jb0 + kg * 8;
  const ushort* bp = gTb + (size_t)(jc * 16 + kg) * 2048 + (h * 64 + il) * 8;

#pragma unroll
  for (int ks = 0; ks < 4; ++ks) {
    const int o = ks * 32;
    unsigned long long w = (ks & 2) ? m1 : m0;
    unsigned byte_ = (unsigned)(w >> ((ks & 1) * 32 + kg * 8)) & 0xffu;

    bf16x8 A;
#pragma unroll
    for (int gp = 0; gp < 2; ++gp) {
      float4 s4 = *(const float4*)(sp + o + gp * 4);
      float4 ee4 = *(const float4*)(eerp + o + gp * 4);
      float4 fe4 = *(const float4*)(ferp + o + gp * 4);
      float sv[4] = {s4.x, s4.y, s4.z, s4.w};
      float ev[4] = {ee4.x, ee4.y, ee4.z, ee4.w};
      float fv[4] = {fe4.x, fe4.y, fe4.z, fe4.w};
#pragma unroll
      for (int e = 0; e < 4; ++e) {
        bool nb = (byte_ >> (gp * 4 + e)) & 1u;
        float spv = __expf(sv[e]) * rz2;
        float p = eel * ev[e];
        float q = fel * fv[e];
        float E = fmaxf(p, q);  // == (p>1 ? p : q)
        float tt = nb ? (E * rz1 + spv) : 0.f;
        float c = __expf(tt);
        z3 += c;
        A[gp * 4 + e] = (short)f2bf(c);
      }
    }

    const ushort* bks = bp + (size_t)(ks * 4) * 2048;
    acc[0] = __builtin_amdgcn_mfma_f32_16x16x32_bf16(A, *(const bf16x8*)(bks), acc[0], 0, 0, 0);
    acc[1] = __builtin_amdgcn_mfma_f32_16x16x32_bf16(A, *(const bf16x8*)(bks + 128), acc[1], 0, 0, 0);
    acc[2] = __builtin_amdgcn_mfma_f32_16x16x32_bf16(A, *(const bf16x8*)(bks + 256), acc[2], 0, 0, 0);
    acc[3] = __builtin_amdgcn_mfma_f32_16x16x32_bf16(A, *(const bf16x8*)(bks + 384), acc[3], 0, 0, 0);
  }

  z3 += __shfl_xor(z3, 16);
  z3 += __shfl_xor(z3, 32);
  if (lane < 16)
    Z3p[jc * (NN * 4) + (i0 + lane) * 4 + h] = z3;

  _Float16* up = U + (size_t)jc * (NN * 256) + (size_t)i0 * 256 + h * 64 + il;
#pragma unroll
  for (int nt = 0; nt < 4; ++nt)
#pragma unroll
    for (int q = 0; q < 4; ++q)
      up[(size_t)(kg * 4 + q) * 256 + nt * 16] = (_Float16)acc[nt][q];
}

// -------- K5: combine 16 partials, divide by Z3 --------
__global__ __launch_bounds__(256) void k_final(
    const _Float16* __restrict__ U, const float* __restrict__ Z3p,
    float* __restrict__ out) {
  const int i = blockIdx.x;
  const int c = threadIdx.x;
  const int h = c >> 6;
  float u = 0.f, z = 0.f;
#pragma unroll
  for (int p = 0; p < 16; ++p) {
    u += (float)U[(size_t)p * (NN * 256) + (size_t)i * 256 + c];
    z += Z3p[p * (NN * 4) + i * 4 + h];
  }
  out[(size_t)i * 256 + c] = u / z;
}

extern "C" void kernel_launch(void* const* d_in, const int* in_sizes, int n_in,
                              void* d_out, int out_size, void* d_ws, size_t ws_size,
                              hipStream_t stream) {
  const float* hin = (const float*)d_in[0];
  const float* adj = (const float*)d_in[1];
  const float* s = (const float*)d_in[2];
  const float* W = (const float*)d_in[3];
  const float* aw = (const float*)d_in[4];
  float* out = (float*)d_out;

  // Workspace layout (f32 slots) — AUDITED, non-overlapping:
  //  el      [       0,    8192)
  //  er      [    8192,   16384)
  //  Eel     [   16384,   24576)
  //  Fel     [   24576,   32768)
  //  Eer_jh  [   32768,   40960)
  //  Fer_jh  [   40960,   49152)
  //  Eer_hj  [   49152,   57344)
  //  Fer_hj  [   57344,   65536)
  //  rZ1     [   65536,   73728)
  //  rZ2     [   73728,   75776)
  //  Z3p     [   75776,  206848)   16 * 8192
  //  maskb   [  206848,  337920)   65536 u64 = 131072 slots
  //  wthi    [  337920,  403456)   131072 ushort = 65536 slots
  //  wtlo    [  403456,  468992)   131072 ushort = 65536 slots
  //  gTb     [  468992,  731136)   524288 ushort = 262144 slots
  //  U       [  731136, 4925440)   16*2048*256 f16 = 4194304 slots
  float* ws = (float*)d_ws;
  float* el     = ws;
  float* er     = ws + 8192;
  float* Eel    = ws + 16384;
  float* Fel    = ws + 24576;
  float* Eer_jh = ws + 32768;
  float* Fer_jh = ws + 40960;
  float* Eer_hj = ws + 49152;
  float* Fer_hj = ws + 57344;
  float* rZ1    = ws + 65536;
  float* rZ2    = ws + 73728;
  float* Z3p    = ws + 75776;
  unsigned long long* maskb = (unsigned long long*)(ws + 206848);
  ushort* wthi  = (ushort*)(ws + 337920);
  ushort* wtlo  = (ushort*)(ws + 403456);
  ushort* gTb   = (ushort*)(ws + 468992);
  _Float16* U   = (_Float16*)(ws + 731136);

  k_wprep<<<32, 256, 0, stream>>>(W, wthi, wtlo);
  k_gemm<<<128, 256, 0, stream>>>(hin, wthi, wtlo, aw, gTb, el, er);
  k_tables<<<8, 256, 0, stream>>>(el, er, Eel, Fel, Eer_jh, Fer_jh, Eer_hj, Fer_hj);
  k_rowz<<<2048, 256, 0, stream>>>(adj, s, Eel, Fel, Eer_jh, Fer_jh, rZ1, rZ2, maskb);
  k_attn<<<2048, 256, 0, stream>>>(s, maskb, gTb, Eel, Fel, Eer_hj, Fer_hj, rZ1, rZ2, U, Z3p);
  k_final<<<2048, 256, 0, stream>>>(U, Z3p, out);
}